// Round 14
// baseline (105.360 us; speedup 1.0000x reference)
//
#include <hip/hip_runtime.h>

#define NN 50000
#define KK 16
#define FF 128
#define NB 32   // nodes per block
#define NW 8    // nodes per wave
#define NEGI -9.0e15f

typedef float fx4 __attribute__((ext_vector_type(4)));
typedef float fx2 __attribute__((ext_vector_type(2)));

template <int CTRL>
__device__ __forceinline__ float dpp_add(float v) {
  int s = __builtin_amdgcn_mov_dpp(__float_as_int(v), CTRL, 0xF, 0xF, true);
  return v + __int_as_float(s);
}
template <int PAT>
__device__ __forceinline__ float swz_add(float v) {
  int s = __builtin_amdgcn_ds_swizzle(__float_as_int(v), PAT);
  return v + __int_as_float(s);
}
// sum across each 32-lane half (halves independent)
__device__ __forceinline__ float red32(float v) {
  v = dpp_add<0xB1>(v);    // + lane^1
  v = dpp_add<0x4E>(v);    // + lane^2
  v = dpp_add<0x141>(v);   // + lane^4
  v = dpp_add<0x140>(v);   // + lane^8
  v = swz_add<0x401F>(v);  // + lane^16
  return v;
}
__device__ __forceinline__ float dot4(float4 a, float4 b) {
  return fmaf(a.x, b.x, fmaf(a.y, b.y, fmaf(a.z, b.z, a.w * b.w)));
}
__device__ __forceinline__ float4 ntload4(const float* p) {
  fx4 v = __builtin_nontemporal_load((const fx4*)p);
  return make_float4(v.x, v.y, v.z, v.w);
}

// pre-kernel: (a) block 0: wa[0:128)=W@a1, wa[128:256)=W@a2
//             (b) all blocks: pack adj -> 16-bit node masks
__global__ void gat_pre(const float* __restrict__ Wm, const float* __restrict__ Av,
                        const int* __restrict__ ADJ, float* __restrict__ wa_out,
                        unsigned* __restrict__ msk_out) {
  const int tid = threadIdx.x;
  const int gi = blockIdx.x * 256 + tid;          // int4 index over ADJ
  if (gi < NN * 4) {
    const int4 a = ((const int4*)ADJ)[gi];
    unsigned nib = (unsigned)(a.x > 0) | ((unsigned)(a.y > 0) << 1) |
                   ((unsigned)(a.z > 0) << 2) | ((unsigned)(a.w > 0) << 3);
    unsigned v = nib << (4 * (gi & 3));
    v |= (unsigned)__shfl_xor((int)v, 1);         // OR across 4-lane quad
    v |= (unsigned)__shfl_xor((int)v, 2);
    if ((gi & 3) == 0) msk_out[gi >> 2] = v;
  }
  if (blockIdx.x == 0) {
    const int f = tid & 127, sel = tid >> 7;
    const float4* W4 = (const float4*)(Wm + f * FF);
    const float4* A4 = (const float4*)(Av + sel * FF);
    float s = 0.f;
#pragma unroll
    for (int u = 0; u < 32; ++u) {
      float4 wv = W4[u], av = A4[u];
      s += wv.x * av.x + wv.y * av.y + wv.z * av.z + wv.w * av.w;
    }
    wa_out[tid] = s;
  }
}

// ---------------- Kernel A: attention -> xa (ws, cached stores -> L3) ------
// Pure stream: masked nt X loads, depth-4 pipeline, no LDS, no phase B.
__global__ __launch_bounds__(256, 2)
void gat_attn(const float* __restrict__ OX, const float* __restrict__ X,
              const unsigned* __restrict__ MSK, const float* __restrict__ WA,
              float* __restrict__ XA) {
  const int tid  = threadIdx.x;
  const int l    = tid & 63;
  const int j    = l & 31;             // feature quad: features 4j..4j+3
  const int half = l >> 5;             // k parity
  const int wu   = __builtin_amdgcn_readfirstlane(tid >> 6);
  const int nbase = blockIdx.x * NB + wu * NW;

  const float4 w1 = ((const float4*)WA)[j];        // (W@a1) quad
  const float4 w2 = ((const float4*)WA)[32 + j];   // (W@a2) quad

  const int limit = (NN - nbase < NW) ? (NN - nbase) : NW;  // may be <=0

  // all 8 node masks upfront: wave-uniform addresses -> scalar loads (SGPRs)
  unsigned mks[NW];
#pragma unroll
  for (int i = 0; i < NW; ++i) mks[i] = (i < limit) ? MSK[nbase + i] : 0u;

  auto PRELOAD = [&](int i, float4* xv, float4& ox) {
    const int n = nbase + i;
    const unsigned ml = mks[i] ? mks[i] : 0xFFFFu;  // load mask (mk==0 -> all)
    const float* xp = X + (size_t)n * (KK * FF);
#pragma unroll
    for (int t = 0; t < 8; ++t) {
      xv[t] = make_float4(0.f, 0.f, 0.f, 0.f);
      if ((ml >> (2 * t + half)) & 1u)              // exec-masked load
        xv[t] = ntload4(xp + (t * 64 + l) * 4);
    }
    ox = ntload4(OX + (size_t)n * FF + j * 4);
  };

  auto PROCA = [&](int i, const float4* xv, float4 ox) {
    const int n = nbase + i;
    const unsigned mk = mks[i];                     // score mask (may be 0)
    const float s0 = red32(dot4(ox, w1));
    float e[8];
#pragma unroll
    for (int t = 0; t < 8; ++t) e[t] = red32(dot4(xv[t], w2)) + s0;

    float m = -3.0e38f;
#pragma unroll
    for (int t = 0; t < 8; ++t) {
      float v = e[t];
      v = fmaxf(v, 0.2f * v);                        // leaky relu
      e[t] = ((mk >> (2 * t + half)) & 1u) ? v : NEGI;
      m = fmaxf(m, e[t]);
    }
    m = fmaxf(m, __shfl_xor(m, 32));                 // global max over 16 k

    float ss = 0.f;
    float4 pacc = {0.f, 0.f, 0.f, 0.f};
#pragma unroll
    for (int t = 0; t < 8; ++t) {
      const float w = __expf(e[t] - m);              // ==0 exactly when masked
      ss += w;
      pacc.x = fmaf(w, xv[t].x, pacc.x);
      pacc.y = fmaf(w, xv[t].y, pacc.y);
      pacc.z = fmaf(w, xv[t].z, pacc.z);
      pacc.w = fmaf(w, xv[t].w, pacc.w);
    }
    ss += __shfl_xor(ss, 32);
    pacc.x += __shfl_xor(pacc.x, 32);
    pacc.y += __shfl_xor(pacc.y, 32);
    pacc.z += __shfl_xor(pacc.z, 32);
    pacc.w += __shfl_xor(pacc.w, 32);
    const float inv = 1.0f / ss;

    float4 xa;
    xa.x = fmaf(inv, pacc.x, ox.x);
    xa.y = fmaf(inv, pacc.y, ox.y);
    xa.z = fmaf(inv, pacc.z, ox.z);
    xa.w = fmaf(inv, pacc.w, ox.w);

    if (half == 0)
      *(float4*)(XA + (size_t)n * FF + 4 * j) = xa;  // cached store -> L3
  };

  // ---- depth-4 straight-line schedule over 8 nodes ----
  float4 xva[8], xvb[8], xvc[8], xvd[8];
  float4 oxa, oxb, oxc, oxd;
  if (0 < limit) PRELOAD(0, xva, oxa);
  if (1 < limit) PRELOAD(1, xvb, oxb);
  if (2 < limit) PRELOAD(2, xvc, oxc);
  if (3 < limit) PRELOAD(3, xvd, oxd);

  if (0 < limit) PROCA(0, xva, oxa);
  if (4 < limit) PRELOAD(4, xva, oxa);
  if (1 < limit) PROCA(1, xvb, oxb);
  if (5 < limit) PRELOAD(5, xvb, oxb);
  if (2 < limit) PROCA(2, xvc, oxc);
  if (6 < limit) PRELOAD(6, xvc, oxc);
  if (3 < limit) PROCA(3, xvd, oxd);
  if (7 < limit) PRELOAD(7, xvd, oxd);

  if (4 < limit) PROCA(4, xva, oxa);
  if (5 < limit) PROCA(5, xvb, oxb);
  if (6 < limit) PROCA(6, xvc, oxc);
  if (7 < limit) PROCA(7, xvd, oxd);
}

// ---------------- Kernel B: out = elu(xa @ W) ----------------
// wave = 8 nodes; stage xa (4KB, L3-hot) to LDS; broadcast xa, coalesced W.
__global__ __launch_bounds__(256, 4)
void gat_out(const float* __restrict__ XA, const float* __restrict__ Wm,
             float* __restrict__ out) {
  __shared__ float xs[4][1024];        // per-wave: 8 nodes x 128 floats

  const int tid = threadIdx.x;
  const int l   = tid & 63;
  const int wu  = __builtin_amdgcn_readfirstlane(tid >> 6);
  const int nbase = blockIdx.x * NB + wu * NW;
  float* xsw = xs[wu];

  const int limit = (NN - nbase < NW) ? (NN - nbase) : NW;
  if (limit <= 0) return;

  // stage xa for 8 nodes: 256 float4s, 4 per lane (guarded)
  const float4* src = (const float4*)(XA + (size_t)nbase * FF);
  const int nq = limit * 32;           // valid float4 count
#pragma unroll
  for (int c = 0; c < 4; ++c) {
    const int idx = c * 64 + l;
    if (idx < nq) ((float4*)xsw)[idx] = src[idx];
  }
  // wave-internal LDS dependency: compiler inserts lgkmcnt wait

  float2 acc[NW];
#pragma unroll
  for (int i = 0; i < NW; ++i) { acc[i].x = 0.f; acc[i].y = 0.f; }

#pragma unroll 4
  for (int q = 0; q < 32; ++q) {
    const float* wr = Wm + (size_t)(4 * q) * FF;
    const float2 wv0 = ((const float2*)(wr))[l];
    const float2 wv1 = ((const float2*)(wr + FF))[l];
    const float2 wv2 = ((const float2*)(wr + 2 * FF))[l];
    const float2 wv3 = ((const float2*)(wr + 3 * FF))[l];
#pragma unroll
    for (int i = 0; i < NW; ++i) {
      const float4 xa4 = ((const float4*)xsw)[i * 32 + q];   // broadcast
      acc[i].x = fmaf(xa4.x, wv0.x, fmaf(xa4.y, wv1.x, fmaf(xa4.z, wv2.x, fmaf(xa4.w, wv3.x, acc[i].x))));
      acc[i].y = fmaf(xa4.x, wv0.y, fmaf(xa4.y, wv1.y, fmaf(xa4.z, wv2.y, fmaf(xa4.w, wv3.y, acc[i].y))));
    }
  }

#pragma unroll
  for (int i = 0; i < NW; ++i) {
    if (i < limit) {
      fx2 st;
      st.x = acc[i].x > 0.f ? acc[i].x : (__expf(acc[i].x) - 1.0f);
      st.y = acc[i].y > 0.f ? acc[i].y : (__expf(acc[i].y) - 1.0f);
      __builtin_nontemporal_store(st, (fx2*)(out + (size_t)(nbase + i) * FF) + l);
    }
  }
}

extern "C" void kernel_launch(void* const* d_in, const int* in_sizes, int n_in,
                              void* d_out, int out_size, void* d_ws, size_t ws_size,
                              hipStream_t stream) {
  const float* OX  = (const float*)d_in[0];
  const float* X   = (const float*)d_in[1];
  const int*   ADJ = (const int*)d_in[2];
  const float* Wm  = (const float*)d_in[3];
  const float* Av  = (const float*)d_in[4];
  float* out = (float*)d_out;
  float* wa  = (float*)d_ws;                       // wa[0:256)
  unsigned* msk = (unsigned*)d_ws + 256;           // masks[0:50000)
  float* XA = (float*)d_ws + 65536;                // xa[50000*128], 256KB offset

  const int preblocks = (NN * 4 + 255) / 256;      // 782
  gat_pre<<<preblocks, 256, 0, stream>>>(Wm, Av, ADJ, wa, msk);
  const int blocks = (NN + NB - 1) / NB;           // 1563
  gat_attn<<<blocks, 256, 0, stream>>>(OX, X, msk, wa, XA);
  gat_out<<<blocks, 256, 0, stream>>>(XA, Wm, out);
}

// Round 15
// 97.177 us; speedup vs baseline: 1.0842x; 1.0842x over previous
//
#include <hip/hip_runtime.h>

#define NN 50000
#define KK 16
#define FF 128
#define NB 16   // nodes per block (4 per wave) — 50000 = 3125 * 16 exactly
#define NW 4
#define NEGI -9.0e15f

typedef float fx4 __attribute__((ext_vector_type(4)));
typedef float fx2 __attribute__((ext_vector_type(2)));

template <int CTRL>
__device__ __forceinline__ float dpp_add(float v) {
  int s = __builtin_amdgcn_mov_dpp(__float_as_int(v), CTRL, 0xF, 0xF, true);
  return v + __int_as_float(s);
}
template <int PAT>
__device__ __forceinline__ float swz_add(float v) {
  int s = __builtin_amdgcn_ds_swizzle(__float_as_int(v), PAT);
  return v + __int_as_float(s);
}
// sum across each 32-lane half (halves independent)
__device__ __forceinline__ float red32(float v) {
  v = dpp_add<0xB1>(v);    // + lane^1
  v = dpp_add<0x4E>(v);    // + lane^2
  v = dpp_add<0x141>(v);   // + lane^4
  v = dpp_add<0x140>(v);   // + lane^8
  v = swz_add<0x401F>(v);  // + lane^16
  return v;
}
__device__ __forceinline__ float dot4(float4 a, float4 b) {
  return fmaf(a.x, b.x, fmaf(a.y, b.y, fmaf(a.z, b.z, a.w * b.w)));
}
__device__ __forceinline__ float4 ntload4(const float* p) {
  fx4 v = __builtin_nontemporal_load((const fx4*)p);
  return make_float4(v.x, v.y, v.z, v.w);
}

// pre-kernel (1 block): wa[0:128)=W@a1, wa[128:256)=W@a2
__global__ void gat_wa(const float* __restrict__ Wm, const float* __restrict__ Av,
                       float* __restrict__ wa_out) {
  const int tid = threadIdx.x;
  const int f = tid & 127, sel = tid >> 7;
  const float4* W4 = (const float4*)(Wm + f * FF);
  const float4* A4 = (const float4*)(Av + sel * FF);
  float s = 0.f;
#pragma unroll
  for (int u = 0; u < 32; ++u) {
    float4 wv = W4[u], av = A4[u];
    s += wv.x * av.x + wv.y * av.y + wv.z * av.z + wv.w * av.w;
  }
  wa_out[tid] = s;
}

// main: barrier-free waves; 4 nodes/wave fully preloaded (masked nt loads);
// in-wave adj->mask (one dword/lane + shfl-OR); monolithic B at the end.
__global__ __launch_bounds__(256, 2)
void gat_fused(const float* __restrict__ OX, const float* __restrict__ X,
               const int* __restrict__ ADJ, const float* __restrict__ WA,
               const float* __restrict__ Wm, float* __restrict__ out) {
  // per-wave xa slots: [slot 0..3][q 0..31][4], slot stride 132 floats
  __shared__ float xs[4 * 4 * 132];

  const int tid  = threadIdx.x;
  const int l    = tid & 63;
  const int j    = l & 31;             // feature quad: features 4j..4j+3
  const int half = l >> 5;             // k parity in phase A
  const int wu   = __builtin_amdgcn_readfirstlane(tid >> 6);
  const int nbase = blockIdx.x * NB + wu * NW;
  float* xsw = xs + wu * (NW * 132);

  // ---- issue adj + all OX loads first (independent of masks) ----
  const int adjv = ADJ[nbase * KK + l];            // 64 ints = 4 nodes' adj
  float4 ox0 = ntload4(OX + (size_t)(nbase + 0) * FF + 4 * j);
  float4 ox1 = ntload4(OX + (size_t)(nbase + 1) * FF + 4 * j);
  float4 ox2 = ntload4(OX + (size_t)(nbase + 2) * FF + 4 * j);
  float4 ox3 = ntload4(OX + (size_t)(nbase + 3) * FF + 4 * j);

  const float4 w1 = ((const float4*)WA)[j];        // (W@a1) quad
  const float4 w2 = ((const float4*)WA)[32 + j];   // (W@a2) quad

  // ---- masks: lane l holds bit (l&15) of node (l>>4); OR within 16-lane grp
  unsigned b = (adjv > 0) ? (1u << (l & 15)) : 0u;
  b |= (unsigned)__shfl_xor((int)b, 1);
  b |= (unsigned)__shfl_xor((int)b, 2);
  b |= (unsigned)__shfl_xor((int)b, 4);
  b |= (unsigned)__shfl_xor((int)b, 8);
  unsigned mks[NW];
  mks[0] = (unsigned)__shfl((int)b, 0);
  mks[1] = (unsigned)__shfl((int)b, 16);
  mks[2] = (unsigned)__shfl((int)b, 32);
  mks[3] = (unsigned)__shfl((int)b, 48);

  auto PRELOAD = [&](int i, float4* xv) {
    const int n = nbase + i;
    const unsigned ml = mks[i] ? mks[i] : 0xFFFFu;  // load mask (mk==0 -> all)
    const float* xp = X + (size_t)n * (KK * FF);
#pragma unroll
    for (int t = 0; t < 8; ++t) {
      xv[t] = make_float4(0.f, 0.f, 0.f, 0.f);
      if ((ml >> (2 * t + half)) & 1u)              // exec-masked load
        xv[t] = ntload4(xp + (t * 64 + l) * 4);
    }
  };

  // attention for one node; xa quad -> LDS slot i
  auto PROCA = [&](int i, const float4* xv, float4 ox) {
    const unsigned mk = mks[i];                     // score mask (may be 0)
    const float s0 = red32(dot4(ox, w1));
    float e[8];
#pragma unroll
    for (int t = 0; t < 8; ++t) e[t] = red32(dot4(xv[t], w2)) + s0;

    float m = -3.0e38f;
#pragma unroll
    for (int t = 0; t < 8; ++t) {
      float v = e[t];
      v = fmaxf(v, 0.2f * v);                        // leaky relu
      e[t] = ((mk >> (2 * t + half)) & 1u) ? v : NEGI;
      m = fmaxf(m, e[t]);
    }
    m = fmaxf(m, __shfl_xor(m, 32));                 // global max over 16 k

    float ss = 0.f;
    float4 pacc = {0.f, 0.f, 0.f, 0.f};
#pragma unroll
    for (int t = 0; t < 8; ++t) {
      const float w = __expf(e[t] - m);              // ==0 exactly when masked
      ss += w;
      pacc.x = fmaf(w, xv[t].x, pacc.x);
      pacc.y = fmaf(w, xv[t].y, pacc.y);
      pacc.z = fmaf(w, xv[t].z, pacc.z);
      pacc.w = fmaf(w, xv[t].w, pacc.w);
    }
    ss += __shfl_xor(ss, 32);
    pacc.x += __shfl_xor(pacc.x, 32);
    pacc.y += __shfl_xor(pacc.y, 32);
    pacc.z += __shfl_xor(pacc.z, 32);
    pacc.w += __shfl_xor(pacc.w, 32);
    const float inv = 1.0f / ss;

    float4 xa;
    xa.x = fmaf(inv, pacc.x, ox.x);
    xa.y = fmaf(inv, pacc.y, ox.y);
    xa.z = fmaf(inv, pacc.z, ox.z);
    xa.w = fmaf(inv, pacc.w, ox.w);

    if (half == 0)
      *(float4*)&xsw[i * 132 + j * 4] = xa;          // ds_write_b128
  };

  // ---- phase A: all 4 nodes preloaded, then processed ----
  {
    float4 xva[8], xvb[8], xvc[8], xvd[8];
    PRELOAD(0, xva);
    PRELOAD(1, xvb);
    PRELOAD(2, xvc);
    PRELOAD(3, xvd);
    PROCA(0, xva, ox0);
    PROCA(1, xvb, ox1);
    PROCA(2, xvc, ox2);
    PROCA(3, xvd, ox3);
  }

  // ---- phase B: out[n, 2l..2l+1] = elu( xa[n,:] @ W[:, 2l..2l+1] ) ----
  float2 acc[NW];
#pragma unroll
  for (int i = 0; i < NW; ++i) { acc[i].x = 0.f; acc[i].y = 0.f; }

#pragma unroll 4
  for (int q = 0; q < 32; ++q) {
    const float* wr = Wm + (size_t)(4 * q) * FF;
    const float2 wv0 = ((const float2*)(wr))[l];
    const float2 wv1 = ((const float2*)(wr + FF))[l];
    const float2 wv2 = ((const float2*)(wr + 2 * FF))[l];
    const float2 wv3 = ((const float2*)(wr + 3 * FF))[l];
#pragma unroll
    for (int i = 0; i < NW; ++i) {
      const float4 xa4 = *(const float4*)&xsw[i * 132 + q * 4];  // broadcast
      acc[i].x = fmaf(xa4.x, wv0.x, fmaf(xa4.y, wv1.x, fmaf(xa4.z, wv2.x, fmaf(xa4.w, wv3.x, acc[i].x))));
      acc[i].y = fmaf(xa4.x, wv0.y, fmaf(xa4.y, wv1.y, fmaf(xa4.z, wv2.y, fmaf(xa4.w, wv3.y, acc[i].y))));
    }
  }

#pragma unroll
  for (int i = 0; i < NW; ++i) {
    fx2 st;
    st.x = acc[i].x > 0.f ? acc[i].x : (__expf(acc[i].x) - 1.0f);
    st.y = acc[i].y > 0.f ? acc[i].y : (__expf(acc[i].y) - 1.0f);
    __builtin_nontemporal_store(st, (fx2*)(out + (size_t)(nbase + i) * FF) + l);
  }
}

extern "C" void kernel_launch(void* const* d_in, const int* in_sizes, int n_in,
                              void* d_out, int out_size, void* d_ws, size_t ws_size,
                              hipStream_t stream) {
  const float* OX  = (const float*)d_in[0];
  const float* X   = (const float*)d_in[1];
  const int*   ADJ = (const int*)d_in[2];
  const float* Wm  = (const float*)d_in[3];
  const float* Av  = (const float*)d_in[4];
  float* out = (float*)d_out;
  float* wa  = (float*)d_ws;                       // wa[0:256)

  gat_wa<<<1, 256, 0, stream>>>(Wm, Av, wa);
  gat_fused<<<NN / NB, 256, 0, stream>>>(OX, X, ADJ, wa, Wm, out);  // 3125
}

// Round 16
// 83.193 us; speedup vs baseline: 1.2665x; 1.1681x over previous
//
#include <hip/hip_runtime.h>

#define NN 50000
#define KK 16
#define FF 128
#define NB 32   // nodes per block
#define NW 8    // nodes per wave
#define NEGI -9.0e15f

typedef float fx4 __attribute__((ext_vector_type(4)));
typedef float fx2 __attribute__((ext_vector_type(2)));

template <int CTRL>
__device__ __forceinline__ float dpp_add(float v) {
  int s = __builtin_amdgcn_mov_dpp(__float_as_int(v), CTRL, 0xF, 0xF, true);
  return v + __int_as_float(s);
}
template <int PAT>
__device__ __forceinline__ float swz_add(float v) {
  int s = __builtin_amdgcn_ds_swizzle(__float_as_int(v), PAT);
  return v + __int_as_float(s);
}
// sum across each 32-lane half (halves independent)
__device__ __forceinline__ float red32(float v) {
  v = dpp_add<0xB1>(v);    // + lane^1
  v = dpp_add<0x4E>(v);    // + lane^2
  v = dpp_add<0x141>(v);   // + lane^4
  v = dpp_add<0x140>(v);   // + lane^8
  v = swz_add<0x401F>(v);  // + lane^16
  return v;
}
__device__ __forceinline__ float dot4(float4 a, float4 b) {
  return fmaf(a.x, b.x, fmaf(a.y, b.y, fmaf(a.z, b.z, a.w * b.w)));
}
__device__ __forceinline__ float4 ntload4(const float* p) {
  fx4 v = __builtin_nontemporal_load((const fx4*)p);
  return make_float4(v.x, v.y, v.z, v.w);
}

// pre-kernel (1 block): wa[0:128)=W@a1, wa[128:256)=W@a2
__global__ void gat_wa(const float* __restrict__ Wm, const float* __restrict__ Av,
                       float* __restrict__ wa_out) {
  const int tid = threadIdx.x;
  const int f = tid & 127, sel = tid >> 7;
  const float4* W4 = (const float4*)(Wm + f * FF);
  const float4* A4 = (const float4*)(Av + sel * FF);
  float s = 0.f;
#pragma unroll
  for (int u = 0; u < 32; ++u) {
    float4 wv = W4[u], av = A4[u];
    s += wv.x * av.x + wv.y * av.y + wv.z * av.z + wv.w * av.w;
  }
  wa_out[tid] = s;
}

// main: barrier-free waves; depth-4 prefetch; in-wave adj->mask;
// mask-predicated nt X loads; monolithic B at the end.
__global__ __launch_bounds__(256, 2)
void gat_fused(const float* __restrict__ OX, const float* __restrict__ X,
               const int* __restrict__ ADJ, const float* __restrict__ WA,
               const float* __restrict__ Wm, float* __restrict__ out) {
  // per-wave xa slots: [slot 0..7][q 0..31][4], slot stride 132 floats
  __shared__ float xs[4 * 8 * 132];

  const int tid  = threadIdx.x;
  const int l    = tid & 63;
  const int j    = l & 31;             // feature quad: features 4j..4j+3
  const int half = l >> 5;             // k parity in phase A
  const int wu   = __builtin_amdgcn_readfirstlane(tid >> 6);
  const int nbase = blockIdx.x * NB + wu * NW;
  float* xsw = xs + wu * (8 * 132);

  const int limit = (NN - nbase < NW) ? (NN - nbase) : NW;
  if (limit <= 0) return;              // tail waves: no nodes, no adj to read

  const float4 w1 = ((const float4*)WA)[j];        // (W@a1) quad
  const float4 w2 = ((const float4*)WA)[32 + j];   // (W@a2) quad

  // ---- in-wave masks: 128 adj ints = 2 coalesced dwords/lane ----
  // (OOB-safe: limit>0 => nbase*KK+127 < NN*KK)
  const int a0 = ADJ[nbase * KK + l];         // nodes 0..3, bit (l&15) of node (l>>4)
  const int a1 = ADJ[nbase * KK + 64 + l];    // nodes 4..7
  unsigned b0 = (a0 > 0) ? (1u << (l & 15)) : 0u;
  unsigned b1 = (a1 > 0) ? (1u << (l & 15)) : 0u;
  b0 |= (unsigned)__shfl_xor((int)b0, 1);  b1 |= (unsigned)__shfl_xor((int)b1, 1);
  b0 |= (unsigned)__shfl_xor((int)b0, 2);  b1 |= (unsigned)__shfl_xor((int)b1, 2);
  b0 |= (unsigned)__shfl_xor((int)b0, 4);  b1 |= (unsigned)__shfl_xor((int)b1, 4);
  b0 |= (unsigned)__shfl_xor((int)b0, 8);  b1 |= (unsigned)__shfl_xor((int)b1, 8);
  unsigned mks[NW];
  mks[0] = (unsigned)__shfl((int)b0, 0);
  mks[1] = (unsigned)__shfl((int)b0, 16);
  mks[2] = (unsigned)__shfl((int)b0, 32);
  mks[3] = (unsigned)__shfl((int)b0, 48);
  mks[4] = (unsigned)__shfl((int)b1, 0);
  mks[5] = (unsigned)__shfl((int)b1, 16);
  mks[6] = (unsigned)__shfl((int)b1, 32);
  mks[7] = (unsigned)__shfl((int)b1, 48);

  auto PRELOAD = [&](int i, float4* xv, float4& ox) {
    const int n = nbase + i;
    const unsigned ml = mks[i] ? mks[i] : 0xFFFFu;  // load mask (mk==0 -> all)
    const float* xp = X + (size_t)n * (KK * FF);
#pragma unroll
    for (int t = 0; t < 8; ++t) {
      xv[t] = make_float4(0.f, 0.f, 0.f, 0.f);
      if ((ml >> (2 * t + half)) & 1u)              // exec-masked load
        xv[t] = ntload4(xp + (t * 64 + l) * 4);
    }
    ox = ntload4(OX + (size_t)n * FF + j * 4);
  };

  // attention for one node; xa quad -> LDS slot i
  auto PROCA = [&](int i, const float4* xv, float4 ox) {
    const unsigned mk = mks[i];                     // score mask (may be 0)
    const float s0 = red32(dot4(ox, w1));
    float e[8];
#pragma unroll
    for (int t = 0; t < 8; ++t) e[t] = red32(dot4(xv[t], w2)) + s0;

    float m = -3.0e38f;
#pragma unroll
    for (int t = 0; t < 8; ++t) {
      float v = e[t];
      v = fmaxf(v, 0.2f * v);                        // leaky relu
      e[t] = ((mk >> (2 * t + half)) & 1u) ? v : NEGI;
      m = fmaxf(m, e[t]);
    }
    m = fmaxf(m, __shfl_xor(m, 32));                 // global max over 16 k

    float ss = 0.f;
    float4 pacc = {0.f, 0.f, 0.f, 0.f};
#pragma unroll
    for (int t = 0; t < 8; ++t) {
      const float w = __expf(e[t] - m);              // ==0 exactly when masked
      ss += w;
      pacc.x = fmaf(w, xv[t].x, pacc.x);
      pacc.y = fmaf(w, xv[t].y, pacc.y);
      pacc.z = fmaf(w, xv[t].z, pacc.z);
      pacc.w = fmaf(w, xv[t].w, pacc.w);
    }
    ss += __shfl_xor(ss, 32);
    pacc.x += __shfl_xor(pacc.x, 32);
    pacc.y += __shfl_xor(pacc.y, 32);
    pacc.z += __shfl_xor(pacc.z, 32);
    pacc.w += __shfl_xor(pacc.w, 32);
    const float inv = 1.0f / ss;

    float4 xa;
    xa.x = fmaf(inv, pacc.x, ox.x);
    xa.y = fmaf(inv, pacc.y, ox.y);
    xa.z = fmaf(inv, pacc.z, ox.z);
    xa.w = fmaf(inv, pacc.w, ox.w);

    if (half == 0)
      *(float4*)&xsw[i * 132 + j * 4] = xa;          // ds_write_b128
  };

  // ---- phase A: depth-4 straight-line schedule over 8 nodes ----
  {
    float4 xva[8], xvb[8], xvc[8], xvd[8];
    float4 oxa, oxb, oxc, oxd;
    if (0 < limit) PRELOAD(0, xva, oxa);
    if (1 < limit) PRELOAD(1, xvb, oxb);
    if (2 < limit) PRELOAD(2, xvc, oxc);
    if (3 < limit) PRELOAD(3, xvd, oxd);

    if (0 < limit) PROCA(0, xva, oxa);
    if (4 < limit) PRELOAD(4, xva, oxa);
    if (1 < limit) PROCA(1, xvb, oxb);
    if (5 < limit) PRELOAD(5, xvb, oxb);
    if (2 < limit) PROCA(2, xvc, oxc);
    if (6 < limit) PRELOAD(6, xvc, oxc);
    if (3 < limit) PROCA(3, xvd, oxd);
    if (7 < limit) PRELOAD(7, xvd, oxd);

    if (4 < limit) PROCA(4, xva, oxa);
    if (5 < limit) PROCA(5, xvb, oxb);
    if (6 < limit) PROCA(6, xvc, oxc);
    if (7 < limit) PROCA(7, xvd, oxd);
  }

  // ---- phase B: out[n, 2l..2l+1] = elu( xa[n,:] @ W[:, 2l..2l+1] ) ----
  float2 acc[NW];
#pragma unroll
  for (int i = 0; i < NW; ++i) { acc[i].x = 0.f; acc[i].y = 0.f; }

#pragma unroll 4
  for (int q = 0; q < 32; ++q) {
    const float* wr = Wm + (size_t)(4 * q) * FF;
    const float2 wv0 = ((const float2*)(wr))[l];
    const float2 wv1 = ((const float2*)(wr + FF))[l];
    const float2 wv2 = ((const float2*)(wr + 2 * FF))[l];
    const float2 wv3 = ((const float2*)(wr + 3 * FF))[l];
#pragma unroll
    for (int i = 0; i < NW; ++i) {
      const float4 xa4 = *(const float4*)&xsw[i * 132 + q * 4];  // broadcast
      acc[i].x = fmaf(xa4.x, wv0.x, fmaf(xa4.y, wv1.x, fmaf(xa4.z, wv2.x, fmaf(xa4.w, wv3.x, acc[i].x))));
      acc[i].y = fmaf(xa4.x, wv0.y, fmaf(xa4.y, wv1.y, fmaf(xa4.z, wv2.y, fmaf(xa4.w, wv3.y, acc[i].y))));
    }
  }

#pragma unroll
  for (int i = 0; i < NW; ++i) {
    const int n2 = nbase + i;
    if (i < limit) {
      fx2 st;
      st.x = acc[i].x > 0.f ? acc[i].x : (__expf(acc[i].x) - 1.0f);
      st.y = acc[i].y > 0.f ? acc[i].y : (__expf(acc[i].y) - 1.0f);
      __builtin_nontemporal_store(st, (fx2*)(out + (size_t)n2 * FF) + l);
    }
  }
}

extern "C" void kernel_launch(void* const* d_in, const int* in_sizes, int n_in,
                              void* d_out, int out_size, void* d_ws, size_t ws_size,
                              hipStream_t stream) {
  const float* OX  = (const float*)d_in[0];
  const float* X   = (const float*)d_in[1];
  const int*   ADJ = (const int*)d_in[2];
  const float* Wm  = (const float*)d_in[3];
  const float* Av  = (const float*)d_in[4];
  float* out = (float*)d_out;
  float* wa  = (float*)d_ws;                       // wa[0:256)

  gat_wa<<<1, 256, 0, stream>>>(Wm, Av, wa);
  const int blocks = (NN + NB - 1) / NB;           // 1563
  gat_fused<<<blocks, 256, 0, stream>>>(OX, X, ADJ, wa, Wm, out);
}

// Round 17
// 78.866 us; speedup vs baseline: 1.3359x; 1.0549x over previous
//
#include <hip/hip_runtime.h>

#define NN 50000
#define KK 16
#define FF 128
#define NB 32   // nodes per block
#define NW 8    // nodes per wave
#define NEGI -9.0e15f

typedef float fx4 __attribute__((ext_vector_type(4)));
typedef float fx2 __attribute__((ext_vector_type(2)));

template <int CTRL>
__device__ __forceinline__ float dpp_add(float v) {
  int s = __builtin_amdgcn_mov_dpp(__float_as_int(v), CTRL, 0xF, 0xF, true);
  return v + __int_as_float(s);
}
template <int PAT>
__device__ __forceinline__ float swz_add(float v) {
  int s = __builtin_amdgcn_ds_swizzle(__float_as_int(v), PAT);
  return v + __int_as_float(s);
}
// sum across each 32-lane half (halves independent)
__device__ __forceinline__ float red32(float v) {
  v = dpp_add<0xB1>(v);    // + lane^1
  v = dpp_add<0x4E>(v);    // + lane^2
  v = dpp_add<0x141>(v);   // + lane^4
  v = dpp_add<0x140>(v);   // + lane^8
  v = swz_add<0x401F>(v);  // + lane^16
  return v;
}
__device__ __forceinline__ float dot4(float4 a, float4 b) {
  return fmaf(a.x, b.x, fmaf(a.y, b.y, fmaf(a.z, b.z, a.w * b.w)));
}
__device__ __forceinline__ float4 ntload4(const float* p) {
  fx4 v = __builtin_nontemporal_load((const fx4*)p);
  return make_float4(v.x, v.y, v.z, v.w);
}

// pre-kernel (1 block): wa[0:128)=W@a1, wa[128:256)=W@a2
__global__ void gat_wa(const float* __restrict__ Wm, const float* __restrict__ Av,
                       float* __restrict__ wa_out) {
  const int tid = threadIdx.x;
  const int f = tid & 127, sel = tid >> 7;
  const float4* W4 = (const float4*)(Wm + f * FF);
  const float4* A4 = (const float4*)(Av + sel * FF);
  float s = 0.f;
#pragma unroll
  for (int u = 0; u < 32; ++u) {
    float4 wv = W4[u], av = A4[u];
    s += wv.x * av.x + wv.y * av.y + wv.z * av.z + wv.w * av.w;
  }
  wa_out[tid] = s;
}

// main: barrier-free waves; depth-3 rolling prefetch @ 3 blocks/CU;
// in-wave adj->mask; mask-predicated nt X loads; monolithic B at the end.
__global__ __launch_bounds__(256, 3)
void gat_fused(const float* __restrict__ OX, const float* __restrict__ X,
               const int* __restrict__ ADJ, const float* __restrict__ WA,
               const float* __restrict__ Wm, float* __restrict__ out) {
  // per-wave xa slots: [slot 0..7][q 0..31][4], slot stride 132 floats
  __shared__ float xs[4 * 8 * 132];

  const int tid  = threadIdx.x;
  const int l    = tid & 63;
  const int j    = l & 31;             // feature quad: features 4j..4j+3
  const int half = l >> 5;             // k parity in phase A
  const int wu   = __builtin_amdgcn_readfirstlane(tid >> 6);
  const int nbase = blockIdx.x * NB + wu * NW;
  float* xsw = xs + wu * (8 * 132);

  const int limit = (NN - nbase < NW) ? (NN - nbase) : NW;
  if (limit <= 0) return;              // tail waves: no nodes, no adj to read

  const float4 w1 = ((const float4*)WA)[j];        // (W@a1) quad
  const float4 w2 = ((const float4*)WA)[32 + j];   // (W@a2) quad

  // ---- in-wave masks: 128 adj ints = 2 coalesced dwords/lane ----
  const int a0 = ADJ[nbase * KK + l];         // nodes 0..3, bit (l&15) of node (l>>4)
  const int a1 = ADJ[nbase * KK + 64 + l];    // nodes 4..7
  unsigned b0 = (a0 > 0) ? (1u << (l & 15)) : 0u;
  unsigned b1 = (a1 > 0) ? (1u << (l & 15)) : 0u;
  b0 |= (unsigned)__shfl_xor((int)b0, 1);  b1 |= (unsigned)__shfl_xor((int)b1, 1);
  b0 |= (unsigned)__shfl_xor((int)b0, 2);  b1 |= (unsigned)__shfl_xor((int)b1, 2);
  b0 |= (unsigned)__shfl_xor((int)b0, 4);  b1 |= (unsigned)__shfl_xor((int)b1, 4);
  b0 |= (unsigned)__shfl_xor((int)b0, 8);  b1 |= (unsigned)__shfl_xor((int)b1, 8);
  unsigned mks[NW];
  mks[0] = (unsigned)__shfl((int)b0, 0);
  mks[1] = (unsigned)__shfl((int)b0, 16);
  mks[2] = (unsigned)__shfl((int)b0, 32);
  mks[3] = (unsigned)__shfl((int)b0, 48);
  mks[4] = (unsigned)__shfl((int)b1, 0);
  mks[5] = (unsigned)__shfl((int)b1, 16);
  mks[6] = (unsigned)__shfl((int)b1, 32);
  mks[7] = (unsigned)__shfl((int)b1, 48);

  auto PRELOAD = [&](int i, float4* xv, float4& ox) {
    const int n = nbase + i;
    const unsigned ml = mks[i] ? mks[i] : 0xFFFFu;  // load mask (mk==0 -> all)
    const float* xp = X + (size_t)n * (KK * FF);
#pragma unroll
    for (int t = 0; t < 8; ++t) {
      xv[t] = make_float4(0.f, 0.f, 0.f, 0.f);
      if ((ml >> (2 * t + half)) & 1u)              // exec-masked load
        xv[t] = ntload4(xp + (t * 64 + l) * 4);
    }
    ox = ntload4(OX + (size_t)n * FF + j * 4);
  };

  // attention for one node; xa quad -> LDS slot i
  auto PROCA = [&](int i, const float4* xv, float4 ox) {
    const unsigned mk = mks[i];                     // score mask (may be 0)
    const float s0 = red32(dot4(ox, w1));
    float e[8];
#pragma unroll
    for (int t = 0; t < 8; ++t) e[t] = red32(dot4(xv[t], w2)) + s0;

    float m = -3.0e38f;
#pragma unroll
    for (int t = 0; t < 8; ++t) {
      float v = e[t];
      v = fmaxf(v, 0.2f * v);                        // leaky relu
      e[t] = ((mk >> (2 * t + half)) & 1u) ? v : NEGI;
      m = fmaxf(m, e[t]);
    }
    m = fmaxf(m, __shfl_xor(m, 32));                 // global max over 16 k

    float ss = 0.f;
    float4 pacc = {0.f, 0.f, 0.f, 0.f};
#pragma unroll
    for (int t = 0; t < 8; ++t) {
      const float w = __expf(e[t] - m);              // ==0 exactly when masked
      ss += w;
      pacc.x = fmaf(w, xv[t].x, pacc.x);
      pacc.y = fmaf(w, xv[t].y, pacc.y);
      pacc.z = fmaf(w, xv[t].z, pacc.z);
      pacc.w = fmaf(w, xv[t].w, pacc.w);
    }
    ss += __shfl_xor(ss, 32);
    pacc.x += __shfl_xor(pacc.x, 32);
    pacc.y += __shfl_xor(pacc.y, 32);
    pacc.z += __shfl_xor(pacc.z, 32);
    pacc.w += __shfl_xor(pacc.w, 32);
    const float inv = 1.0f / ss;

    float4 xa;
    xa.x = fmaf(inv, pacc.x, ox.x);
    xa.y = fmaf(inv, pacc.y, ox.y);
    xa.z = fmaf(inv, pacc.z, ox.z);
    xa.w = fmaf(inv, pacc.w, ox.w);

    if (half == 0)
      *(float4*)&xsw[i * 132 + j * 4] = xa;          // ds_write_b128
  };

  // ---- phase A: depth-3 rolling schedule over 8 nodes ----
  {
    float4 xva[8], xvb[8], xvc[8];
    float4 oxa, oxb, oxc;
    if (0 < limit) PRELOAD(0, xva, oxa);
    if (1 < limit) PRELOAD(1, xvb, oxb);
    if (2 < limit) PRELOAD(2, xvc, oxc);

    if (0 < limit) PROCA(0, xva, oxa);
    if (3 < limit) PRELOAD(3, xva, oxa);
    if (1 < limit) PROCA(1, xvb, oxb);
    if (4 < limit) PRELOAD(4, xvb, oxb);
    if (2 < limit) PROCA(2, xvc, oxc);
    if (5 < limit) PRELOAD(5, xvc, oxc);
    if (3 < limit) PROCA(3, xva, oxa);
    if (6 < limit) PRELOAD(6, xva, oxa);
    if (4 < limit) PROCA(4, xvb, oxb);
    if (7 < limit) PRELOAD(7, xvb, oxb);
    if (5 < limit) PROCA(5, xvc, oxc);
    if (6 < limit) PROCA(6, xva, oxa);
    if (7 < limit) PROCA(7, xvb, oxb);
  }

  // ---- phase B: out[n, 2l..2l+1] = elu( xa[n,:] @ W[:, 2l..2l+1] ) ----
  float2 acc[NW];
#pragma unroll
  for (int i = 0; i < NW; ++i) { acc[i].x = 0.f; acc[i].y = 0.f; }

#pragma unroll 4
  for (int q = 0; q < 32; ++q) {
    const float* wr = Wm + (size_t)(4 * q) * FF;
    const float2 wv0 = ((const float2*)(wr))[l];
    const float2 wv1 = ((const float2*)(wr + FF))[l];
    const float2 wv2 = ((const float2*)(wr + 2 * FF))[l];
    const float2 wv3 = ((const float2*)(wr + 3 * FF))[l];
#pragma unroll
    for (int i = 0; i < NW; ++i) {
      const float4 xa4 = *(const float4*)&xsw[i * 132 + q * 4];  // broadcast
      acc[i].x = fmaf(xa4.x, wv0.x, fmaf(xa4.y, wv1.x, fmaf(xa4.z, wv2.x, fmaf(xa4.w, wv3.x, acc[i].x))));
      acc[i].y = fmaf(xa4.x, wv0.y, fmaf(xa4.y, wv1.y, fmaf(xa4.z, wv2.y, fmaf(xa4.w, wv3.y, acc[i].y))));
    }
  }

#pragma unroll
  for (int i = 0; i < NW; ++i) {
    const int n2 = nbase + i;
    if (i < limit) {
      fx2 st;
      st.x = acc[i].x > 0.f ? acc[i].x : (__expf(acc[i].x) - 1.0f);
      st.y = acc[i].y > 0.f ? acc[i].y : (__expf(acc[i].y) - 1.0f);
      __builtin_nontemporal_store(st, (fx2*)(out + (size_t)n2 * FF) + l);
    }
  }
}

extern "C" void kernel_launch(void* const* d_in, const int* in_sizes, int n_in,
                              void* d_out, int out_size, void* d_ws, size_t ws_size,
                              hipStream_t stream) {
  const float* OX  = (const float*)d_in[0];
  const float* X   = (const float*)d_in[1];
  const int*   ADJ = (const int*)d_in[2];
  const float* Wm  = (const float*)d_in[3];
  const float* Av  = (const float*)d_in[4];
  float* out = (float*)d_out;
  float* wa  = (float*)d_ws;                       // wa[0:256)

  gat_wa<<<1, 256, 0, stream>>>(Wm, Av, wa);
  const int blocks = (NN + NB - 1) / NB;           // 1563
  gat_fused<<<blocks, 256, 0, stream>>>(OX, X, ADJ, wa, Wm, out);
}